// Round 6
// baseline (60.789 us; speedup 1.0000x reference)
//
#include <hip/hip_runtime.h>

// Depthwise xcorr: out[p][oy][ox] = sum_{ky,kx} x[p][oy+ky][ox+kx] * z[p][ky][kx]
// 32768 planes. x: 31x31, z: 7x7, out: 25x25, fp32.
//
// Round 6: kill the LDS bank conflicts (round 5: 14.66M conflict cycles ~24us
// of LDS-pipe time; stride 31 = -1 mod 32 made tile diagonals 5-way conflict).
//  - LDS x row stride 37 (= 5 mod 32): bank = 5*(5ty+tx) -> 25 distinct banks
//    per plane, cross-plane chains <=3-way (~free).
//  - global_load_lds writes linearly, so the GLOBAL source address is
//    pre-swizzled per lane (padded-slot -> packed element, pad cols clamped).
//  - PPB=8 -> 38912 B LDS -> 4 blocks/CU (round 5's exact 40960 fit got 3).

#define PPB 8
#define WX 31
#define RS 37                  // padded LDS row stride (5 mod 32)
#define XPLANE 961             // 31*31 packed global plane
#define LDSPLANE (31 * RS)     // 1147
#define ZPLANE 49
#define OPLANE 625
#define WO 25
#define XFLOATS (PPB * LDSPLANE)          // 9176
#define XCHUNKS ((XFLOATS + 255) / 256)   // 36
#define XSLOTS (XCHUNKS * 256)            // 9216 floats = 36864 B
#define ZFLOATS (PPB * ZPLANE)            // 392
#define ZCHUNKS 2
#define ZSLOTS (ZCHUNKS * 256)            // 512 floats = 2048 B

typedef __attribute__((address_space(1))) const void gaddr_t;
typedef __attribute__((address_space(3))) void laddr_t;

__global__ __launch_bounds__(256, 4) void dwxcorr_kernel(
    const float* __restrict__ z, const float* __restrict__ x,
    float* __restrict__ out, int nplanes) {
  __shared__ float xs[XSLOTS];  // 36864 B, padded stride-37 planes
  __shared__ float zs[ZSLOTS];  //  2048 B -> total 38912 B -> 4 blocks/CU

  const int tid = threadIdx.x;
  const int p0 = blockIdx.x * PPB;   // nplanes % PPB == 0 (32768/8)
  const long xoff = (long)p0 * XPLANE;
  const long zoff = (long)p0 * ZPLANE;
  const int wbase = tid & ~63;  // wave-uniform LDS chunk base

  // ---- stage x: LDS linear, global source pre-swizzled (padded->packed) ----
  // slot s in padded space: pp = s/1147, r = (s%1147)/37, col = s%37 (clamp 30)
  {
    int slot0 = tid;            // chunk 0 slot
    int pp = 0, rem = tid;      // tid < 256 < 1147
#pragma unroll
    for (int c = 0; c < XCHUNKS; ++c) {
      int rr = rem;
      int ppc = pp;
      // clamp the 40 overhang slots (9176..9215) into the last plane
      if (c == XCHUNKS - 1 && ppc >= PPB) { ppc = PPB - 1; rr = LDSPLANE - 1; }
      int r = rr / RS;
      int col = rr - r * RS;
      col = (col > 30) ? 30 : col;  // pad cols duplicate col 30 (never read)
      long gi = xoff + ppc * XPLANE + r * WX + col;
      __builtin_amdgcn_global_load_lds((gaddr_t*)(x + gi),
                                       (laddr_t*)&xs[c * 256 + wbase], 4, 0, 0);
      // advance slot by 256 in padded space (256 < 1147: at most one wrap)
      rem += 256;
      if (rem >= LDSPLANE) { rem -= LDSPLANE; pp++; }
      (void)slot0;
    }
  }
  // ---- stage z: fully linear ----
#pragma unroll
  for (int c = 0; c < ZCHUNKS; ++c) {
    int s = c * 256 + tid;
    if (s >= ZFLOATS) s = ZFLOATS - 1;  // dup, never read
    __builtin_amdgcn_global_load_lds((gaddr_t*)(z + zoff + s),
                                     (laddr_t*)&zs[c * 256 + wbase], 4, 0, 0);
  }
  __syncthreads();  // drains vmcnt before barrier

  // ---- compute: thread -> (plane pp, 5x5 tile (ty,tx)); 200/256 active ----
  if (tid >= PPB * 25) return;
  const int pp = tid / 25;
  const int t25 = tid - pp * 25;
  const int ty = t25 / 5;
  const int tx = t25 - ty * 5;

  float zr[ZPLANE];
#pragma unroll
  for (int j = 0; j < ZPLANE; ++j) zr[j] = zs[pp * ZPLANE + j];

  float acc[5][5];
#pragma unroll
  for (int r = 0; r < 5; ++r)
#pragma unroll
    for (int j = 0; j < 5; ++j) acc[r][j] = 0.0f;

  const float* xbase = &xs[pp * LDSPLANE + (ty * 5) * RS + tx * 5];

  // Stream 11 patch rows; row iy feeds output rows orow = iy-ky in [0,4]
#pragma unroll
  for (int iy = 0; iy < 11; ++iy) {
    float xr[11];
#pragma unroll
    for (int k = 0; k < 11; ++k) xr[k] = xbase[iy * RS + k];
    const int ky_lo = (iy - 4 < 0) ? 0 : iy - 4;
    const int ky_hi = (iy < 6) ? iy : 6;
#pragma unroll
    for (int ky = 0; ky < 7; ++ky) {
      if (ky < ky_lo || ky > ky_hi) continue;  // compile-time folded
      const int orow = iy - ky;
#pragma unroll
      for (int kx = 0; kx < 7; ++kx) {
        const float zv = zr[ky * 7 + kx];
#pragma unroll
        for (int j = 0; j < 5; ++j)
          acc[orow][j] = fmaf(xr[kx + j], zv, acc[orow][j]);
      }
    }
  }

  // ---- write the 5x5 tile ----
  float* ob = out + (size_t)(p0 + pp) * OPLANE + (ty * 5) * WO + tx * 5;
#pragma unroll
  for (int r = 0; r < 5; ++r)
#pragma unroll
    for (int j = 0; j < 5; ++j) ob[r * WO + j] = acc[r][j];
}

extern "C" void kernel_launch(void* const* d_in, const int* in_sizes, int n_in,
                              void* d_out, int out_size, void* d_ws, size_t ws_size,
                              hipStream_t stream) {
  const float* z = (const float*)d_in[0];  // [B,C,7,7]
  const float* x = (const float*)d_in[1];  // [B,C,31,31]
  float* out = (float*)d_out;              // [B,C,25,25]

  const int nplanes = in_sizes[0] / ZPLANE;      // 32768
  const int blocks = (nplanes + PPB - 1) / PPB;  // 4096

  hipLaunchKernelGGL(dwxcorr_kernel, dim3(blocks), dim3(256), 0, stream,
                     z, x, out, nplanes);
}